// Round 8
// baseline (896.258 us; speedup 1.0000x reference)
//
#include <hip/hip_runtime.h>
#include <stdint.h>
#include <stddef.h>

#define FT_IN 41024
#define KHALF 256
#define BATCH 8192
#define NKT 641          // 41024 / 64 K-tiles

typedef __attribute__((ext_vector_type(8))) short short8;
typedef __attribute__((ext_vector_type(4))) short short4v;
typedef __attribute__((ext_vector_type(4))) float f32x4;
typedef __attribute__((ext_vector_type(2))) uint32_t u32x2;

typedef const __attribute__((address_space(1))) uint32_t* gas1_t;
typedef __attribute__((address_space(3))) uint32_t* las3_t;

// fp32 -> bf16 RNE (bit trick) — used only in the small wprep pass
__device__ __forceinline__ unsigned short f2bf(float f) {
  union { float f; uint32_t u; } x; x.f = f;
  uint32_t u = x.u + 0x7FFFu + ((x.u >> 16) & 1u);
  return (unsigned short)(u >> 16);
}

#define MFMA16(acc, a, b) \
  asm("v_mfma_f32_16x16x32_bf16 %0, %1, %2, %0" : "+v"(acc) : "v"(a), "v"(b))

// packed fp32x2 -> bf16x2 (RNE), lo -> bits[15:0]
#define CVTPK(dst, lo, hi) \
  asm("v_cvt_pk_bf16_f32 %0, %1, %2" : "=v"(dst) : "v"(lo), "v"(hi))

// ---------------- kernel 1: ft_w fp32 -> bf16 ----------------
__global__ void wprep_kernel(const float* __restrict__ w,
                             unsigned short* __restrict__ o, int n4) {
  int i = blockIdx.x * blockDim.x + threadIdx.x;
  int stride = gridDim.x * blockDim.x;
  for (; i < n4; i += stride) {
    f32x4 v = ((const f32x4*)w)[i];
    short4v b;
    b.x = (short)f2bf(v.x); b.y = (short)f2bf(v.y);
    b.z = (short)f2bf(v.z); b.w = (short)f2bf(v.w);
    ((short4v*)o)[i] = b;
  }
}

// ---------------- kernel 2: feature-transform GEMM ----------------
// grid: 64 rowblocks x 2 sets x KS kchunks (512 WGs = 2/CU); block 256.
// per-WG tile: 128 rows x 256 cols (features read ONCE), BK=64.
// A: fp32 global -> regs (TWO K-tiles buffered; loads for t+1,t+2 issued
// interleaved per row = 512 B/row DRAM bursts for page locality) ->
// v_cvt_pk_bf16 -> LDS (XOR-swizzled). W: bf16 global -> global_load_lds
// (source pre-swizzled), double-buffered (2x32KB). Raw barrier after MFMA
// keeps prefetch in flight. XCD-chunked bid swizzle for L2 locality.
__global__ __launch_bounds__(256, 2) void ftgemm_kernel(
    const float* __restrict__ f1g, const float* __restrict__ f2g,
    const unsigned short* __restrict__ wb,
    float* __restrict__ part, int KS) {
  __shared__ alignas(16) char sA[16384];
  __shared__ alignas(16) char sW[2][32768];

  // XCD-aware chunked swizzle (nwg = 128*KS, divisible by 8 for KS in {1,2,4})
  const int nwg = (int)gridDim.x;
  const int orig = (int)blockIdx.x;
  int bid = (orig & 7) * (nwg >> 3) + (orig >> 3);

  const int rb = bid & 63; bid >>= 6;
  const int st = bid & 1;  bid >>= 1;
  const int ks = bid;

  const int kt0 = (ks * NKT) / KS;
  const int kt1 = ((ks + 1) * NKT) / KS;
  const int nloc = kt1 - kt0;        // >= 160 for KS<=4

  const int tid  = (int)threadIdx.x;
  const int lane = tid & 63;
  const int wv   = tid >> 6;
  const int wr   = (wv >> 1) << 6;   // wave row offset: 0 / 64
  const int wc   = (wv & 1) << 7;    // wave col offset: 0 / 128
  const int r16  = lane & 15;
  const int hi   = lane >> 4;

  const float* F = (st ? f2g : f1g) + (size_t)rb * (128ull * FT_IN);

  // A staging: thread covers rows (i*16 + tid>>4), k-chunk (tid&15)*4 floats
  const int arow = tid >> 4;
  const int akc  = tid & 15;
  const float* aptr = F + (size_t)arow * FT_IN + (size_t)kt0 * 64 + akc * 4;

  // W staging (global_load_lds, linear LDS dest): chunk c = i*256+tid,
  // row = c>>3 (i adds 32 rows), kc = c&7; source XOR-pre-swizzled.
  const int wrow = tid >> 3;
  const int wkc  = tid & 7;
  const int wkcs = wkc ^ (wrow & 7);
  const unsigned short* wptr =
      wb + (size_t)wrow * FT_IN + (size_t)kt0 * 64;

  f32x4 aregA[8], aregB[8];
  f32x4 acc[4][8];
  const f32x4 fzero = {0.f, 0.f, 0.f, 0.f};
  #pragma unroll
  for (int m = 0; m < 4; ++m)
    #pragma unroll
    for (int n = 0; n < 8; ++n) acc[m][n] = fzero;

  // prologue: A tiles 0,1 -> aregA/aregB (paired per row = 512 B bursts);
  // W glds for tile 0
  #pragma unroll
  for (int i = 0; i < 8; ++i) {
    const float* p = aptr + (size_t)i * (16ull * FT_IN);
    aregA[i] = *(const f32x4*)p;
    aregB[i] = *(const f32x4*)(p + 64);
  }
  #pragma unroll
  for (int i = 0; i < 8; ++i) {
    const unsigned short* g = wptr + (size_t)i * (32ull * FT_IN) + wkcs * 8;
    __builtin_amdgcn_global_load_lds((gas1_t)g,
        (las3_t)&sW[0][(i * 256 + tid) * 16], 16, 0, 0);
  }

  const int sAo = (akc * 8) ^ ((arow & 7) << 4);  // arow&7 == row&7 (row=i*16+arow)
  int buf = 0;
  for (int it = 0; it < nloc; ++it) {
    // phase A: cvt + store A tile (parity selects reg bank; uniform branch)
    if ((it & 1) == 0) {
      #pragma unroll
      for (int i = 0; i < 8; ++i) {
        f32x4 v = aregA[i];
        uint32_t b0, b1;
        CVTPK(b0, v.x, v.y);
        CVTPK(b1, v.z, v.w);
        u32x2 b; b.x = b0; b.y = b1;
        *(u32x2*)(sA + (i * 16 + arow) * 128 + sAo) = b;
      }
    } else {
      #pragma unroll
      for (int i = 0; i < 8; ++i) {
        f32x4 v = aregB[i];
        uint32_t b0, b1;
        CVTPK(b0, v.x, v.y);
        CVTPK(b1, v.z, v.w);
        u32x2 b; b.x = b0; b.y = b1;
        *(u32x2*)(sA + (i * 16 + arow) * 128 + sAo) = b;
      }
    }
    // barrier 1: drains W(it) glds (issued one iteration ago — near free)
    __syncthreads();

    // phase B: at odd it both reg banks are free -> issue tiles it+1, it+2
    // with the two 256 B chunks of each row back-to-back (512 B burst).
    if (it & 1) {
      const float* ap1 = aptr + (size_t)(it + 1) * 64;
      if (it + 2 < nloc) {
        #pragma unroll
        for (int i = 0; i < 8; ++i) {
          const float* p = ap1 + (size_t)i * (16ull * FT_IN);
          aregA[i] = *(const f32x4*)p;
          aregB[i] = *(const f32x4*)(p + 64);
        }
      } else if (it + 1 < nloc) {
        #pragma unroll
        for (int i = 0; i < 8; ++i)
          aregA[i] = *(const f32x4*)(ap1 + (size_t)i * (16ull * FT_IN));
      }
    }
    if (it + 1 < nloc) {
      const unsigned short* wp = wptr + (size_t)(it + 1) * 64;
      #pragma unroll
      for (int i = 0; i < 8; ++i) {
        const unsigned short* g = wp + (size_t)i * (32ull * FT_IN) + wkcs * 8;
        __builtin_amdgcn_global_load_lds((gas1_t)g,
            (las3_t)&sW[buf ^ 1][(i * 256 + tid) * 16], 16, 0, 0);
      }
    }

    // phase C: MFMA
    const char* sWb = sW[buf];
    const int swz = (r16 & 7) << 4;
    #pragma unroll
    for (int k2 = 0; k2 < 2; ++k2) {
      const int ko = (k2 * 64 + hi * 16) ^ swz;
      short8 av[4], bv[8];
      #pragma unroll
      for (int m = 0; m < 4; ++m)
        av[m] = *(const short8*)(sA + (wr + m * 16 + r16) * 128 + ko);
      #pragma unroll
      for (int n = 0; n < 8; ++n)
        bv[n] = *(const short8*)(sWb + (wc + n * 16 + r16) * 128 + ko);
      #pragma unroll
      for (int m = 0; m < 4; ++m)
        #pragma unroll
        for (int n = 0; n < 8; ++n)
          MFMA16(acc[m][n], av[m], bv[n]);
    }

    // barrier 2: RAW s_barrier — no vmcnt drain; prefetch stays in flight.
    __builtin_amdgcn_sched_barrier(0);
    __builtin_amdgcn_s_barrier();
    __builtin_amdgcn_sched_barrier(0);
    buf ^= 1;
  }

  // epilogue: raw partials [ks*2+set][col][row]; D frag: col = lane&15,
  // row = (lane>>4)*4 + reg (4 regs = 4 consecutive rows -> f32x4 store)
  float* pb = part + (size_t)(ks * 2 + st) * (KHALF * (size_t)BATCH);
  const int growb = rb * 128 + wr + hi * 4;
  const int gcolb = wc + r16;
  #pragma unroll
  for (int n = 0; n < 8; ++n)
    #pragma unroll
    for (int m = 0; m < 4; ++m)
      *(f32x4*)(pb + (size_t)(gcolb + n * 16) * BATCH + (growb + m * 16)) =
          acc[m][n];
}

// ---------------- kernel 3: tail MLP ----------------
// 256 blocks x 32 rows. Thread (r = tid&31, cg = tid>>5): row r, 64 cols
// [cg*64, cg*64+64). a1-partials reduced across the 8 col-groups via LDS.
__global__ __launch_bounds__(256) void tail_kernel(
    const float* __restrict__ part,
    const float* __restrict__ ftb, const float* __restrict__ h1w,
    const float* __restrict__ h1b, const float* __restrict__ h2w,
    const float* __restrict__ h2b, const float* __restrict__ outw,
    const float* __restrict__ outb, float* __restrict__ out, int KS) {
  __shared__ float sh1t[512 * 36];   // h1_w transposed [c][j], stride 36 (pad)
  __shared__ float sh2[32 * 32];
  __shared__ float sow[32];
  __shared__ float sh1b[32];
  __shared__ float sh2b[32];
  __shared__ float sftb[256];
  __shared__ float sob[1];

  const int tid = (int)threadIdx.x;
  // coalesced global read (c fast), strided LDS write
  for (int i = tid; i < 512 * 32; i += 256) {
    const int j = i >> 9, c = i & 511;
    sh1t[c * 36 + j] = h1w[i];       // h1w[j][c]
  }
  for (int i = tid; i < 1024; i += 256) sh2[i] = h2w[i];
  if (tid < 32) { sow[tid] = outw[tid]; sh1b[tid] = h1b[tid]; sh2b[tid] = h2b[tid]; }
  sftb[tid] = ftb[tid];
  if (tid == 0) sob[0] = outb[0];
  __syncthreads();

  const int r  = tid & 31;
  const int cg = tid >> 5;
  const int t  = (int)blockIdx.x * 32 + r;   // global batch row

  float a1p[32];
  #pragma unroll
  for (int j = 0; j < 32; ++j) a1p[j] = 0.f;

  for (int ci = 0; ci < 64; ++ci) {
    const int c   = cg * 64 + ci;
    const int set = c >> 8;
    const int cs  = c & 255;
    float v = sftb[cs];
    const float* p = part + ((size_t)set * KHALF + cs) * BATCH + t;
    for (int kq = 0; kq < KS; ++kq)
      v += p[(size_t)kq * (2ull * KHALF * BATCH)];
    v = fminf(fmaxf(v, 0.f), 1.f);
    const f32x4* wr4 = (const f32x4*)(sh1t + c * 36);
    #pragma unroll
    for (int q = 0; q < 8; ++q) {
      f32x4 wv = wr4[q];
      a1p[q * 4 + 0] += v * wv.x; a1p[q * 4 + 1] += v * wv.y;
      a1p[q * 4 + 2] += v * wv.z; a1p[q * 4 + 3] += v * wv.w;
    }
  }

  // reduce the 8 col-group partials per row via LDS (reuse sh1t region)
  float* red = sh1t;                  // [8][32][33]
  __syncthreads();
  #pragma unroll
  for (int j = 0; j < 32; ++j)
    red[(cg * 32 + r) * 33 + j] = a1p[j];
  __syncthreads();

  if (tid < 32) {
    float a1[32];
    #pragma unroll
    for (int j = 0; j < 32; ++j) a1[j] = sh1b[j];
    for (int g = 0; g < 8; ++g)
      #pragma unroll
      for (int j = 0; j < 32; ++j)
        a1[j] += red[(g * 32 + tid) * 33 + j];
    #pragma unroll
    for (int j = 0; j < 32; ++j) a1[j] = fminf(fmaxf(a1[j], 0.f), 1.f);

    float a2[32];
    #pragma unroll
    for (int j = 0; j < 32; ++j) {
      float x = sh2b[j];
      const f32x4* w2 = (const f32x4*)(sh2 + j * 32);
      #pragma unroll
      for (int q = 0; q < 8; ++q) {
        f32x4 wv = w2[q];
        x += a1[q * 4 + 0] * wv.x + a1[q * 4 + 1] * wv.y +
             a1[q * 4 + 2] * wv.z + a1[q * 4 + 3] * wv.w;
      }
      a2[j] = fminf(fmaxf(x, 0.f), 1.f);
    }
    float o = sob[0];
    #pragma unroll
    for (int j = 0; j < 32; ++j) o += a2[j] * sow[j];
    out[(int)blockIdx.x * 32 + tid] = o;
  }
}

// ---------------- launch ----------------
extern "C" void kernel_launch(void* const* d_in, const int* in_sizes, int n_in,
                              void* d_out, int out_size, void* d_ws, size_t ws_size,
                              hipStream_t stream) {
  const float* f1   = (const float*)d_in[0];
  const float* f2   = (const float*)d_in[1];
  const float* ftw  = (const float*)d_in[2];
  const float* ftb  = (const float*)d_in[3];
  const float* h1w  = (const float*)d_in[4];
  const float* h1b  = (const float*)d_in[5];
  const float* h2w  = (const float*)d_in[6];
  const float* h2b  = (const float*)d_in[7];
  const float* outw = (const float*)d_in[8];
  const float* outb = (const float*)d_in[9];
  float* out = (float*)d_out;

  unsigned short* wb = (unsigned short*)d_ws;
  const size_t woff = (size_t)KHALF * FT_IN * 2;            // 21,004,288 B
  float* part = (float*)((char*)d_ws + woff);
  const size_t per = 2ull * KHALF * BATCH * 4;              // 16,777,216 B / kchunk

  // KS=4 -> 64rb x 2set x 4 = 512 WGs = exactly 2 WGs/CU (80 KB LDS), 1 round
  int KS = 1;
  if (ws_size >= woff + 4 * per)      KS = 4;
  else if (ws_size >= woff + 2 * per) KS = 2;

  wprep_kernel<<<2048, 256, 0, stream>>>(ftw, wb, (KHALF * FT_IN) / 4);
  ftgemm_kernel<<<dim3(64 * 2 * KS), 256, 0, stream>>>(f1, f2, wb, part, KS);
  tail_kernel<<<BATCH / 32, 256, 0, stream>>>(part, ftb, h1w, h1b, h2w, h2b,
                                              outw, outb, out, KS);
}

// Round 11
// 716.402 us; speedup vs baseline: 1.2511x; 1.2511x over previous
//
#include <hip/hip_runtime.h>
#include <stdint.h>
#include <stddef.h>

#define FT_IN 41024
#define KHALF 256
#define BATCH 8192
#define NKT 641          // 41024 / 64 K-tiles

typedef __attribute__((ext_vector_type(8))) short short8;
typedef __attribute__((ext_vector_type(4))) short short4v;
typedef __attribute__((ext_vector_type(4))) float f32x4;
typedef __attribute__((ext_vector_type(2))) uint32_t u32x2;

typedef const __attribute__((address_space(1))) uint32_t* gas1_t;
typedef __attribute__((address_space(3))) uint32_t* las3_t;

// fp32 -> bf16 RNE (bit trick) — used only in the small wprep pass
__device__ __forceinline__ unsigned short f2bf(float f) {
  union { float f; uint32_t u; } x; x.f = f;
  uint32_t u = x.u + 0x7FFFu + ((x.u >> 16) & 1u);
  return (unsigned short)(u >> 16);
}

#define MFMA16(acc, a, b) \
  asm("v_mfma_f32_16x16x32_bf16 %0, %1, %2, %0" : "+v"(acc) : "v"(a), "v"(b))

// packed fp32x2 -> bf16x2 (RNE), lo -> bits[15:0]
#define CVTPK(dst, lo, hi) \
  asm("v_cvt_pk_bf16_f32 %0, %1, %2" : "=v"(dst) : "v"(lo), "v"(hi))

// ---------------- kernel 1: ft_w fp32 -> bf16 ----------------
__global__ void wprep_kernel(const float* __restrict__ w,
                             unsigned short* __restrict__ o, int n4) {
  int i = blockIdx.x * blockDim.x + threadIdx.x;
  int stride = gridDim.x * blockDim.x;
  for (; i < n4; i += stride) {
    f32x4 v = ((const f32x4*)w)[i];
    short4v b;
    b.x = (short)f2bf(v.x); b.y = (short)f2bf(v.y);
    b.z = (short)f2bf(v.z); b.w = (short)f2bf(v.w);
    ((short4v*)o)[i] = b;
  }
}

// ---------------- kernel 2: feature-transform GEMM ----------------
// grid: 64 rowblocks x 2 sets x KS kchunks (512 WGs); block 512 (8 waves).
// per-WG tile: 128 rows x 256 cols (features read ONCE), BK=64. Each wave
// owns a 64x64 output subtile -> acc = 4x4 frags = 64 VGPR/thread, so two
// 8-wave WGs fit per CU (16 waves/CU) with 80 KB LDS (sA 16K + sW 2x32K).
// A: fp32 global -> areg -> v_cvt_pk_bf16 -> LDS (XOR-swizzled). W: bf16
// global -> global_load_lds (source pre-swizzled), double-buffered.
// Plain __syncthreads barriers (raw s_barrier measured neutral in r4->r6).
__global__ __launch_bounds__(512, 4) void ftgemm_kernel(
    const float* __restrict__ f1g, const float* __restrict__ f2g,
    const unsigned short* __restrict__ wb,
    float* __restrict__ part, int KS) {
  __shared__ alignas(16) char sA[16384];
  __shared__ alignas(16) char sW[2][32768];

  // XCD-aware chunked swizzle (nwg = 128*KS, divisible by 8 for KS in {1,2,4})
  const int nwg = (int)gridDim.x;
  const int orig = (int)blockIdx.x;
  int bid = (orig & 7) * (nwg >> 3) + (orig >> 3);

  const int rb = bid & 63; bid >>= 6;
  const int st = bid & 1;  bid >>= 1;
  const int ks = bid;

  const int kt0 = (ks * NKT) / KS;
  const int kt1 = ((ks + 1) * NKT) / KS;
  const int nloc = kt1 - kt0;

  const int tid  = (int)threadIdx.x;
  const int lane = tid & 63;
  const int wv   = tid >> 6;         // 0..7
  const int wr   = (wv >> 2) << 6;   // wave row offset: 0 / 64
  const int wc   = (wv & 3) << 6;    // wave col offset: 0/64/128/192
  const int r16  = lane & 15;
  const int hi   = lane >> 4;

  const float* F = (st ? f2g : f1g) + (size_t)rb * (128ull * FT_IN);

  // A staging: 512 threads cover 128x64 fp32. thread: rows i*32 + (tid>>4)
  // (i=0..3), k-chunk (tid&15)*4 floats.
  const int arow = tid >> 4;         // 0..31
  const int akc  = tid & 15;
  const float* aptr = F + (size_t)arow * FT_IN + (size_t)kt0 * 64 + akc * 4;

  // W staging (global_load_lds, linear LDS dest): chunk c = i*512+tid,
  // row = c>>3 (i adds 64 rows), kc = c&7; source XOR-pre-swizzled.
  const int wrow = tid >> 3;         // 0..63; (row&7) invariant in i
  const int wkc  = tid & 7;
  const int wkcs = wkc ^ (wrow & 7);
  const unsigned short* wptr =
      wb + (size_t)wrow * FT_IN + (size_t)kt0 * 64;

  f32x4 areg[4];
  f32x4 acc[4][4];
  const f32x4 fzero = {0.f, 0.f, 0.f, 0.f};
  #pragma unroll
  for (int m = 0; m < 4; ++m)
    #pragma unroll
    for (int n = 0; n < 4; ++n) acc[m][n] = fzero;

  // prologue: A regs + W glds for tile kt0
  #pragma unroll
  for (int i = 0; i < 4; ++i)
    areg[i] = *(const f32x4*)(aptr + (size_t)i * (32ull * FT_IN));
  #pragma unroll
  for (int i = 0; i < 4; ++i) {
    const unsigned short* g = wptr + (size_t)i * (64ull * FT_IN) + wkcs * 8;
    __builtin_amdgcn_global_load_lds((gas1_t)g,
        (las3_t)&sW[0][(i * 512 + tid) * 16], 16, 0, 0);
  }

  const int sAo = (akc * 8) ^ ((arow & 7) << 4);  // row&7 == arow&7
  int buf = 0;
  for (int it = 0; it < nloc; ++it) {
    // phase A: cvt + store A tile (swizzle: byte ^= (row&7)<<4)
    #pragma unroll
    for (int i = 0; i < 4; ++i) {
      f32x4 v = areg[i];
      uint32_t b0, b1;
      CVTPK(b0, v.x, v.y);
      CVTPK(b1, v.z, v.w);
      u32x2 b; b.x = b0; b.y = b1;
      *(u32x2*)(sA + (i * 32 + arow) * 128 + sAo) = b;
    }
    // barrier 1: sA(t) visible; all waves' W(t) glds landed in sW[buf]
    __syncthreads();

    // phase B: issue next tile's loads
    if (it + 1 < nloc) {
      const float* ap = aptr + (size_t)(it + 1) * 64;
      #pragma unroll
      for (int i = 0; i < 4; ++i)
        areg[i] = *(const f32x4*)(ap + (size_t)i * (32ull * FT_IN));
      const unsigned short* wp = wptr + (size_t)(it + 1) * 64;
      #pragma unroll
      for (int i = 0; i < 4; ++i) {
        const unsigned short* g = wp + (size_t)i * (64ull * FT_IN) + wkcs * 8;
        __builtin_amdgcn_global_load_lds((gas1_t)g,
            (las3_t)&sW[buf ^ 1][(i * 512 + tid) * 16], 16, 0, 0);
      }
    }

    // phase C: MFMA (av[4] live, bv loaded one at a time -> low reg peak)
    const char* sWb = sW[buf];
    const int swz = (r16 & 7) << 4;
    #pragma unroll
    for (int k2 = 0; k2 < 2; ++k2) {
      const int ko = (k2 * 64 + hi * 16) ^ swz;
      short8 av[4];
      #pragma unroll
      for (int m = 0; m < 4; ++m)
        av[m] = *(const short8*)(sA + (wr + m * 16 + r16) * 128 + ko);
      #pragma unroll
      for (int n = 0; n < 4; ++n) {
        short8 bv = *(const short8*)(sWb + (wc + n * 16 + r16) * 128 + ko);
        #pragma unroll
        for (int m = 0; m < 4; ++m)
          MFMA16(acc[m][n], av[m], bv);
      }
    }

    // barrier 2: protects sA/sW[buf] from next iteration's overwrites
    __syncthreads();
    buf ^= 1;
  }

  // epilogue: raw partials [ks*2+set][col][row]; D frag: col = lane&15,
  // row = (lane>>4)*4 + reg (4 regs = 4 consecutive rows -> f32x4 store)
  float* pb = part + (size_t)(ks * 2 + st) * (KHALF * (size_t)BATCH);
  const int growb = rb * 128 + wr + hi * 4;
  const int gcolb = wc + r16;
  #pragma unroll
  for (int n = 0; n < 4; ++n)
    #pragma unroll
    for (int m = 0; m < 4; ++m)
      *(f32x4*)(pb + (size_t)(gcolb + n * 16) * BATCH + (growb + m * 16)) =
          acc[m][n];
}

// ---------------- kernel 3: tail MLP ----------------
// 256 blocks x 32 rows. Thread (r = tid&31, cg = tid>>5): row r, 64 cols
// [cg*64, cg*64+64). a1-partials reduced across the 8 col-groups via LDS.
__global__ __launch_bounds__(256) void tail_kernel(
    const float* __restrict__ part,
    const float* __restrict__ ftb, const float* __restrict__ h1w,
    const float* __restrict__ h1b, const float* __restrict__ h2w,
    const float* __restrict__ h2b, const float* __restrict__ outw,
    const float* __restrict__ outb, float* __restrict__ out, int KS) {
  __shared__ float sh1t[512 * 36];   // h1_w transposed [c][j], stride 36 (pad)
  __shared__ float sh2[32 * 32];
  __shared__ float sow[32];
  __shared__ float sh1b[32];
  __shared__ float sh2b[32];
  __shared__ float sftb[256];
  __shared__ float sob[1];

  const int tid = (int)threadIdx.x;
  // coalesced global read (c fast), strided LDS write
  for (int i = tid; i < 512 * 32; i += 256) {
    const int j = i >> 9, c = i & 511;
    sh1t[c * 36 + j] = h1w[i];       // h1w[j][c]
  }
  for (int i = tid; i < 1024; i += 256) sh2[i] = h2w[i];
  if (tid < 32) { sow[tid] = outw[tid]; sh1b[tid] = h1b[tid]; sh2b[tid] = h2b[tid]; }
  sftb[tid] = ftb[tid];
  if (tid == 0) sob[0] = outb[0];
  __syncthreads();

  const int r  = tid & 31;
  const int cg = tid >> 5;
  const int t  = (int)blockIdx.x * 32 + r;   // global batch row

  float a1p[32];
  #pragma unroll
  for (int j = 0; j < 32; ++j) a1p[j] = 0.f;

  for (int ci = 0; ci < 64; ++ci) {
    const int c   = cg * 64 + ci;
    const int set = c >> 8;
    const int cs  = c & 255;
    float v = sftb[cs];
    const float* p = part + ((size_t)set * KHALF + cs) * BATCH + t;
    for (int kq = 0; kq < KS; ++kq)
      v += p[(size_t)kq * (2ull * KHALF * BATCH)];
    v = fminf(fmaxf(v, 0.f), 1.f);
    const f32x4* wr4 = (const f32x4*)(sh1t + c * 36);
    #pragma unroll
    for (int q = 0; q < 8; ++q) {
      f32x4 wv = wr4[q];
      a1p[q * 4 + 0] += v * wv.x; a1p[q * 4 + 1] += v * wv.y;
      a1p[q * 4 + 2] += v * wv.z; a1p[q * 4 + 3] += v * wv.w;
    }
  }

  // reduce the 8 col-group partials per row via LDS (reuse sh1t region)
  float* red = sh1t;                  // [8][32][33]
  __syncthreads();
  #pragma unroll
  for (int j = 0; j < 32; ++j)
    red[(cg * 32 + r) * 33 + j] = a1p[j];
  __syncthreads();

  if (tid < 32) {
    float a1[32];
    #pragma unroll
    for (int j = 0; j < 32; ++j) a1[j] = sh1b[j];
    for (int g = 0; g < 8; ++g)
      #pragma unroll
      for (int j = 0; j < 32; ++j)
        a1[j] += red[(g * 32 + tid) * 33 + j];
    #pragma unroll
    for (int j = 0; j < 32; ++j) a1[j] = fminf(fmaxf(a1[j], 0.f), 1.f);

    float a2[32];
    #pragma unroll
    for (int j = 0; j < 32; ++j) {
      float x = sh2b[j];
      const f32x4* w2 = (const f32x4*)(sh2 + j * 32);
      #pragma unroll
      for (int q = 0; q < 8; ++q) {
        f32x4 wv = w2[q];
        x += a1[q * 4 + 0] * wv.x + a1[q * 4 + 1] * wv.y +
             a1[q * 4 + 2] * wv.z + a1[q * 4 + 3] * wv.w;
      }
      a2[j] = fminf(fmaxf(x, 0.f), 1.f);
    }
    float o = sob[0];
    #pragma unroll
    for (int j = 0; j < 32; ++j) o += a2[j] * sow[j];
    out[(int)blockIdx.x * 32 + tid] = o;
  }
}

// ---------------- launch ----------------
extern "C" void kernel_launch(void* const* d_in, const int* in_sizes, int n_in,
                              void* d_out, int out_size, void* d_ws, size_t ws_size,
                              hipStream_t stream) {
  const float* f1   = (const float*)d_in[0];
  const float* f2   = (const float*)d_in[1];
  const float* ftw  = (const float*)d_in[2];
  const float* ftb  = (const float*)d_in[3];
  const float* h1w  = (const float*)d_in[4];
  const float* h1b  = (const float*)d_in[5];
  const float* h2w  = (const float*)d_in[6];
  const float* h2b  = (const float*)d_in[7];
  const float* outw = (const float*)d_in[8];
  const float* outb = (const float*)d_in[9];
  float* out = (float*)d_out;

  unsigned short* wb = (unsigned short*)d_ws;
  const size_t woff = (size_t)KHALF * FT_IN * 2;            // 21,004,288 B
  float* part = (float*)((char*)d_ws + woff);
  const size_t per = 2ull * KHALF * BATCH * 4;              // 16,777,216 B / kchunk

  // KS=4 -> 64rb x 2set x 4 = 512 WGs of 512 thr = 2 WGs/CU (80 KB LDS)
  int KS = 1;
  if (ws_size >= woff + 4 * per)      KS = 4;
  else if (ws_size >= woff + 2 * per) KS = 2;

  wprep_kernel<<<2048, 256, 0, stream>>>(ftw, wb, (KHALF * FT_IN) / 4);
  ftgemm_kernel<<<dim3(64 * 2 * KS), 512, 0, stream>>>(f1, f2, wb, part, KS);
  tail_kernel<<<BATCH / 32, 256, 0, stream>>>(part, ftb, h1w, h1b, h2w, h2b,
                                              outw, outb, out, KS);
}

// Round 12
// 687.713 us; speedup vs baseline: 1.3032x; 1.0417x over previous
//
#include <hip/hip_runtime.h>
#include <stdint.h>
#include <stddef.h>

#define FT_IN 41024
#define KHALF 256
#define BATCH 8192
#define NKT 641          // 41024 / 64 K-tiles

typedef __attribute__((ext_vector_type(8))) short short8;
typedef __attribute__((ext_vector_type(4))) short short4v;
typedef __attribute__((ext_vector_type(4))) float f32x4;
typedef __attribute__((ext_vector_type(2))) uint32_t u32x2;

typedef const __attribute__((address_space(1))) uint32_t* gas1_t;
typedef __attribute__((address_space(3))) uint32_t* las3_t;

// fp32 -> bf16 RNE (bit trick) — used only in the small wprep pass
__device__ __forceinline__ unsigned short f2bf(float f) {
  union { float f; uint32_t u; } x; x.f = f;
  uint32_t u = x.u + 0x7FFFu + ((x.u >> 16) & 1u);
  return (unsigned short)(u >> 16);
}

#define MFMA16(acc, a, b) \
  asm("v_mfma_f32_16x16x32_bf16 %0, %1, %2, %0" : "+v"(acc) : "v"(a), "v"(b))

// packed fp32x2 -> bf16x2 (RNE), lo -> bits[15:0]
#define CVTPK(dst, lo, hi) \
  asm("v_cvt_pk_bf16_f32 %0, %1, %2" : "=v"(dst) : "v"(lo), "v"(hi))

// ---------------- kernel 1: ft_w fp32 -> bf16 ----------------
__global__ void wprep_kernel(const float* __restrict__ w,
                             unsigned short* __restrict__ o, int n4) {
  int i = blockIdx.x * blockDim.x + threadIdx.x;
  int stride = gridDim.x * blockDim.x;
  for (; i < n4; i += stride) {
    f32x4 v = ((const f32x4*)w)[i];
    short4v b;
    b.x = (short)f2bf(v.x); b.y = (short)f2bf(v.y);
    b.z = (short)f2bf(v.z); b.w = (short)f2bf(v.w);
    ((short4v*)o)[i] = b;
  }
}

// ---------------- kernel 2: feature-transform GEMM ----------------
// grid: 64 rowblocks x 2 sets x KS kchunks (512 WGs = 2/CU); block 256
// (4 waves, each owns 64x128 of the 128x256 tile; acc[4][8]). BK=64.
// A: fp32 global -> TWO parity register banks (depth-2 prefetch: phase B(t)
// issues A(t+2) into the bank freed by phase A(t); consume-lag = one full
// iteration >> HBM latency) -> v_cvt_pk_bf16 -> LDS (XOR-swizzled).
// W: bf16 global -> global_load_lds (source pre-swizzled), double-buffered.
// barrier1 = __syncthreads (drains only 1-iteration-old loads, ~free);
// barrier2 = raw s_barrier (keeps A(t+2)/W(t+1) in flight).
__global__ __launch_bounds__(256, 2) void ftgemm_kernel(
    const float* __restrict__ f1g, const float* __restrict__ f2g,
    const unsigned short* __restrict__ wb,
    float* __restrict__ part, int KS) {
  __shared__ alignas(16) char sA[16384];
  __shared__ alignas(16) char sW[2][32768];

  // XCD-aware chunked swizzle (nwg = 128*KS, divisible by 8 for KS in {1,2,4})
  const int nwg = (int)gridDim.x;
  const int orig = (int)blockIdx.x;
  int bid = (orig & 7) * (nwg >> 3) + (orig >> 3);

  const int rb = bid & 63; bid >>= 6;
  const int st = bid & 1;  bid >>= 1;
  const int ks = bid;

  const int kt0 = (ks * NKT) / KS;
  const int kt1 = ((ks + 1) * NKT) / KS;
  const int nloc = kt1 - kt0;        // >= 160 for KS<=4

  const int tid  = (int)threadIdx.x;
  const int lane = tid & 63;
  const int wv   = tid >> 6;
  const int wr   = (wv >> 1) << 6;   // wave row offset: 0 / 64
  const int wc   = (wv & 1) << 7;    // wave col offset: 0 / 128
  const int r16  = lane & 15;
  const int hi   = lane >> 4;

  const float* F = (st ? f2g : f1g) + (size_t)rb * (128ull * FT_IN);

  // A staging: thread covers rows (i*16 + tid>>4), k-chunk (tid&15)*4 floats
  const int arow = tid >> 4;
  const int akc  = tid & 15;
  const float* aptr = F + (size_t)arow * FT_IN + (size_t)kt0 * 64 + akc * 4;

  // W staging (global_load_lds, linear LDS dest): chunk c = i*256+tid,
  // row = c>>3 (i adds 32 rows), kc = c&7; source XOR-pre-swizzled.
  const int wrow = tid >> 3;
  const int wkc  = tid & 7;
  const int wkcs = wkc ^ (wrow & 7);
  const unsigned short* wptr =
      wb + (size_t)wrow * FT_IN + (size_t)kt0 * 64;

  f32x4 aregA[8], aregB[8];
  f32x4 acc[4][8];
  const f32x4 fzero = {0.f, 0.f, 0.f, 0.f};
  #pragma unroll
  for (int m = 0; m < 4; ++m)
    #pragma unroll
    for (int n = 0; n < 8; ++n) acc[m][n] = fzero;

  // prologue: A tiles 0 -> bankA, 1 -> bankB; W glds for tile 0
  #pragma unroll
  for (int i = 0; i < 8; ++i)
    aregA[i] = *(const f32x4*)(aptr + (size_t)i * (16ull * FT_IN));
  #pragma unroll
  for (int i = 0; i < 8; ++i)
    aregB[i] = *(const f32x4*)(aptr + 64 + (size_t)i * (16ull * FT_IN));
  #pragma unroll
  for (int i = 0; i < 8; ++i) {
    const unsigned short* g = wptr + (size_t)i * (32ull * FT_IN) + wkcs * 8;
    __builtin_amdgcn_global_load_lds((gas1_t)g,
        (las3_t)&sW[0][(i * 256 + tid) * 16], 16, 0, 0);
  }

  const int sAo = (akc * 8) ^ ((arow & 7) << 4);  // arow&7 == row&7
  int buf = 0;
  for (int it = 0; it < nloc; ++it) {
    // phase A: cvt + store A(it) from parity bank (uniform branch, static idx)
    if ((it & 1) == 0) {
      #pragma unroll
      for (int i = 0; i < 8; ++i) {
        f32x4 v = aregA[i];
        uint32_t b0, b1;
        CVTPK(b0, v.x, v.y);
        CVTPK(b1, v.z, v.w);
        u32x2 b; b.x = b0; b.y = b1;
        *(u32x2*)(sA + (i * 16 + arow) * 128 + sAo) = b;
      }
    } else {
      #pragma unroll
      for (int i = 0; i < 8; ++i) {
        f32x4 v = aregB[i];
        uint32_t b0, b1;
        CVTPK(b0, v.x, v.y);
        CVTPK(b1, v.z, v.w);
        u32x2 b; b.x = b0; b.y = b1;
        *(u32x2*)(sA + (i * 16 + arow) * 128 + sAo) = b;
      }
    }
    // barrier 1: full drain — outstanding loads here (W(it), A(it+1)) were
    // issued one full iteration ago, so the vmcnt(0) is nearly free.
    __syncthreads();

    // phase B: issue A(it+2) into the bank just freed; issue W(it+1) glds.
    if (it + 2 < nloc) {
      const float* ap = aptr + (size_t)(it + 2) * 64;
      if ((it & 1) == 0) {
        #pragma unroll
        for (int i = 0; i < 8; ++i)
          aregA[i] = *(const f32x4*)(ap + (size_t)i * (16ull * FT_IN));
      } else {
        #pragma unroll
        for (int i = 0; i < 8; ++i)
          aregB[i] = *(const f32x4*)(ap + (size_t)i * (16ull * FT_IN));
      }
    }
    if (it + 1 < nloc) {
      const unsigned short* wp = wptr + (size_t)(it + 1) * 64;
      #pragma unroll
      for (int i = 0; i < 8; ++i) {
        const unsigned short* g = wp + (size_t)i * (32ull * FT_IN) + wkcs * 8;
        __builtin_amdgcn_global_load_lds((gas1_t)g,
            (las3_t)&sW[buf ^ 1][(i * 256 + tid) * 16], 16, 0, 0);
      }
    }

    // phase C: MFMA
    const char* sWb = sW[buf];
    const int swz = (r16 & 7) << 4;
    #pragma unroll
    for (int k2 = 0; k2 < 2; ++k2) {
      const int ko = (k2 * 64 + hi * 16) ^ swz;
      short8 av[4], bv[8];
      #pragma unroll
      for (int m = 0; m < 4; ++m)
        av[m] = *(const short8*)(sA + (wr + m * 16 + r16) * 128 + ko);
      #pragma unroll
      for (int n = 0; n < 8; ++n)
        bv[n] = *(const short8*)(sWb + (wc + n * 16 + r16) * 128 + ko);
      #pragma unroll
      for (int m = 0; m < 4; ++m)
        #pragma unroll
        for (int n = 0; n < 8; ++n)
          MFMA16(acc[m][n], av[m], bv[n]);
    }

    // barrier 2: RAW s_barrier — no vmcnt drain; A(it+2)/W(it+1) stay in
    // flight. All phase-C ds_reads were consumed by MFMAs above (compiler
    // lgkmcnt waits precede MFMA issue), so no lgkm wait needed here.
    __builtin_amdgcn_sched_barrier(0);
    __builtin_amdgcn_s_barrier();
    __builtin_amdgcn_sched_barrier(0);
    buf ^= 1;
  }

  // epilogue: raw partials [ks*2+set][col][row]; D frag: col = lane&15,
  // row = (lane>>4)*4 + reg (4 regs = 4 consecutive rows -> f32x4 store)
  float* pb = part + (size_t)(ks * 2 + st) * (KHALF * (size_t)BATCH);
  const int growb = rb * 128 + wr + hi * 4;
  const int gcolb = wc + r16;
  #pragma unroll
  for (int n = 0; n < 8; ++n)
    #pragma unroll
    for (int m = 0; m < 4; ++m)
      *(f32x4*)(pb + (size_t)(gcolb + n * 16) * BATCH + (growb + m * 16)) =
          acc[m][n];
}

// ---------------- kernel 3: tail MLP ----------------
// 256 blocks x 32 rows. Thread (r = tid&31, cg = tid>>5): row r, 64 cols
// [cg*64, cg*64+64). a1-partials reduced across the 8 col-groups via LDS.
__global__ __launch_bounds__(256) void tail_kernel(
    const float* __restrict__ part,
    const float* __restrict__ ftb, const float* __restrict__ h1w,
    const float* __restrict__ h1b, const float* __restrict__ h2w,
    const float* __restrict__ h2b, const float* __restrict__ outw,
    const float* __restrict__ outb, float* __restrict__ out, int KS) {
  __shared__ float sh1t[512 * 36];   // h1_w transposed [c][j], stride 36 (pad)
  __shared__ float sh2[32 * 32];
  __shared__ float sow[32];
  __shared__ float sh1b[32];
  __shared__ float sh2b[32];
  __shared__ float sftb[256];
  __shared__ float sob[1];

  const int tid = (int)threadIdx.x;
  // coalesced global read (c fast), strided LDS write
  for (int i = tid; i < 512 * 32; i += 256) {
    const int j = i >> 9, c = i & 511;
    sh1t[c * 36 + j] = h1w[i];       // h1w[j][c]
  }
  for (int i = tid; i < 1024; i += 256) sh2[i] = h2w[i];
  if (tid < 32) { sow[tid] = outw[tid]; sh1b[tid] = h1b[tid]; sh2b[tid] = h2b[tid]; }
  sftb[tid] = ftb[tid];
  if (tid == 0) sob[0] = outb[0];
  __syncthreads();

  const int r  = tid & 31;
  const int cg = tid >> 5;
  const int t  = (int)blockIdx.x * 32 + r;   // global batch row

  float a1p[32];
  #pragma unroll
  for (int j = 0; j < 32; ++j) a1p[j] = 0.f;

  for (int ci = 0; ci < 64; ++ci) {
    const int c   = cg * 64 + ci;
    const int set = c >> 8;
    const int cs  = c & 255;
    float v = sftb[cs];
    const float* p = part + ((size_t)set * KHALF + cs) * BATCH + t;
    for (int kq = 0; kq < KS; ++kq)
      v += p[(size_t)kq * (2ull * KHALF * BATCH)];
    v = fminf(fmaxf(v, 0.f), 1.f);
    const f32x4* wr4 = (const f32x4*)(sh1t + c * 36);
    #pragma unroll
    for (int q = 0; q < 8; ++q) {
      f32x4 wv = wr4[q];
      a1p[q * 4 + 0] += v * wv.x; a1p[q * 4 + 1] += v * wv.y;
      a1p[q * 4 + 2] += v * wv.z; a1p[q * 4 + 3] += v * wv.w;
    }
  }

  // reduce the 8 col-group partials per row via LDS (reuse sh1t region)
  float* red = sh1t;                  // [8][32][33]
  __syncthreads();
  #pragma unroll
  for (int j = 0; j < 32; ++j)
    red[(cg * 32 + r) * 33 + j] = a1p[j];
  __syncthreads();

  if (tid < 32) {
    float a1[32];
    #pragma unroll
    for (int j = 0; j < 32; ++j) a1[j] = sh1b[j];
    for (int g = 0; g < 8; ++g)
      #pragma unroll
      for (int j = 0; j < 32; ++j)
        a1[j] += red[(g * 32 + tid) * 33 + j];
    #pragma unroll
    for (int j = 0; j < 32; ++j) a1[j] = fminf(fmaxf(a1[j], 0.f), 1.f);

    float a2[32];
    #pragma unroll
    for (int j = 0; j < 32; ++j) {
      float x = sh2b[j];
      const f32x4* w2 = (const f32x4*)(sh2 + j * 32);
      #pragma unroll
      for (int q = 0; q < 8; ++q) {
        f32x4 wv = w2[q];
        x += a1[q * 4 + 0] * wv.x + a1[q * 4 + 1] * wv.y +
             a1[q * 4 + 2] * wv.z + a1[q * 4 + 3] * wv.w;
      }
      a2[j] = fminf(fmaxf(x, 0.f), 1.f);
    }
    float o = sob[0];
    #pragma unroll
    for (int j = 0; j < 32; ++j) o += a2[j] * sow[j];
    out[(int)blockIdx.x * 32 + tid] = o;
  }
}

// ---------------- launch ----------------
extern "C" void kernel_launch(void* const* d_in, const int* in_sizes, int n_in,
                              void* d_out, int out_size, void* d_ws, size_t ws_size,
                              hipStream_t stream) {
  const float* f1   = (const float*)d_in[0];
  const float* f2   = (const float*)d_in[1];
  const float* ftw  = (const float*)d_in[2];
  const float* ftb  = (const float*)d_in[3];
  const float* h1w  = (const float*)d_in[4];
  const float* h1b  = (const float*)d_in[5];
  const float* h2w  = (const float*)d_in[6];
  const float* h2b  = (const float*)d_in[7];
  const float* outw = (const float*)d_in[8];
  const float* outb = (const float*)d_in[9];
  float* out = (float*)d_out;

  unsigned short* wb = (unsigned short*)d_ws;
  const size_t woff = (size_t)KHALF * FT_IN * 2;            // 21,004,288 B
  float* part = (float*)((char*)d_ws + woff);
  const size_t per = 2ull * KHALF * BATCH * 4;              // 16,777,216 B / kchunk

  // KS=4 -> 64rb x 2set x 4 = 512 WGs = exactly 2 WGs/CU (80 KB LDS), 1 round
  int KS = 1;
  if (ws_size >= woff + 4 * per)      KS = 4;
  else if (ws_size >= woff + 2 * per) KS = 2;

  wprep_kernel<<<2048, 256, 0, stream>>>(ftw, wb, (KHALF * FT_IN) / 4);
  ftgemm_kernel<<<dim3(64 * 2 * KS), 256, 0, stream>>>(f1, f2, wb, part, KS);
  tail_kernel<<<BATCH / 32, 256, 0, stream>>>(part, ftb, h1w, h1b, h2w, h2b,
                                              outw, outb, out, KS);
}

// Round 14
// 653.469 us; speedup vs baseline: 1.3715x; 1.0524x over previous
//
#include <hip/hip_runtime.h>
#include <stdint.h>
#include <stddef.h>

#define FT_IN 41024
#define KHALF 256
#define BATCH 8192
#define NKT 641          // 41024 / 64 K-tiles

typedef __attribute__((ext_vector_type(8))) short short8;
typedef __attribute__((ext_vector_type(4))) short short4v;
typedef __attribute__((ext_vector_type(4))) float f32x4;
typedef __attribute__((ext_vector_type(2))) uint32_t u32x2;
typedef __attribute__((ext_vector_type(4))) _Float16 half4v;

typedef const __attribute__((address_space(1))) uint32_t* gas1_t;
typedef __attribute__((address_space(3))) uint32_t* las3_t;

// fp32 -> bf16 RNE (bit trick) — used only in the small wprep pass
__device__ __forceinline__ unsigned short f2bf(float f) {
  union { float f; uint32_t u; } x; x.f = f;
  uint32_t u = x.u + 0x7FFFu + ((x.u >> 16) & 1u);
  return (unsigned short)(u >> 16);
}

#define MFMA16(acc, a, b) \
  asm("v_mfma_f32_16x16x32_bf16 %0, %1, %2, %0" : "+v"(acc) : "v"(a), "v"(b))

// packed fp32x2 -> bf16x2 (RNE), lo -> bits[15:0]
#define CVTPK(dst, lo, hi) \
  asm("v_cvt_pk_bf16_f32 %0, %1, %2" : "=v"(dst) : "v"(lo), "v"(hi))

// ---------------- kernel 1: ft_w fp32 -> bf16 ----------------
__global__ void wprep_kernel(const float* __restrict__ w,
                             unsigned short* __restrict__ o, int n4) {
  int i = blockIdx.x * blockDim.x + threadIdx.x;
  int stride = gridDim.x * blockDim.x;
  for (; i < n4; i += stride) {
    f32x4 v = ((const f32x4*)w)[i];
    short4v b;
    b.x = (short)f2bf(v.x); b.y = (short)f2bf(v.y);
    b.z = (short)f2bf(v.z); b.w = (short)f2bf(v.w);
    ((short4v*)o)[i] = b;
  }
}

// ---------------- kernel 2: feature-transform GEMM ----------------
// (R4 structure, proven 665 us / absmax 2.44e-4; only the epilogue dtype
// changed to fp16 partials.)
// grid: 64 rowblocks x 2 sets x KS kchunks (512 WGs = 2/CU); block 256.
// per-WG tile: 128 rows x 256 cols (features read ONCE), BK=64.
// A: fp32 global -> v_cvt_pk_bf16 -> LDS (XOR-swizzled). W: bf16 global ->
// global_load_lds (source pre-swizzled), double-buffered (2x32KB).
// barrier1 = __syncthreads (drains 1-iteration-old W glds, ~free);
// barrier2 = raw s_barrier (A(t+1)/W(t+1) prefetch stays in flight).
__global__ __launch_bounds__(256, 2) void ftgemm_kernel(
    const float* __restrict__ f1g, const float* __restrict__ f2g,
    const unsigned short* __restrict__ wb,
    _Float16* __restrict__ part, int KS) {
  __shared__ alignas(16) char sA[16384];
  __shared__ alignas(16) char sW[2][32768];

  // XCD-aware chunked swizzle (nwg = 128*KS, divisible by 8 for KS in {1,2,4})
  const int nwg = (int)gridDim.x;
  const int orig = (int)blockIdx.x;
  int bid = (orig & 7) * (nwg >> 3) + (orig >> 3);

  const int rb = bid & 63; bid >>= 6;
  const int st = bid & 1;  bid >>= 1;
  const int ks = bid;

  const int kt0 = (ks * NKT) / KS;
  const int kt1 = ((ks + 1) * NKT) / KS;

  const int tid  = (int)threadIdx.x;
  const int lane = tid & 63;
  const int wv   = tid >> 6;
  const int wr   = (wv >> 1) << 6;   // wave row offset: 0 / 64
  const int wc   = (wv & 1) << 7;    // wave col offset: 0 / 128
  const int r16  = lane & 15;
  const int hi   = lane >> 4;

  const float* F = (st ? f2g : f1g) + (size_t)rb * (128ull * FT_IN);

  // A staging: thread covers rows (i*16 + tid>>4), k-chunk (tid&15)*4 floats
  const int arow = tid >> 4;
  const int akc  = tid & 15;
  const float* aptr = F + (size_t)arow * FT_IN + (size_t)kt0 * 64 + akc * 4;

  // W staging (global_load_lds, linear LDS dest): chunk c = i*256+tid,
  // row = c>>3 (i adds 32 rows), kc = c&7; source XOR-pre-swizzled.
  const int wrow = tid >> 3;
  const int wkc  = tid & 7;
  const int wkcs = wkc ^ (wrow & 7);
  const unsigned short* wptr =
      wb + (size_t)wrow * FT_IN + (size_t)kt0 * 64;

  f32x4 areg[8];
  f32x4 acc[4][8];
  const f32x4 fzero = {0.f, 0.f, 0.f, 0.f};
  #pragma unroll
  for (int m = 0; m < 4; ++m)
    #pragma unroll
    for (int n = 0; n < 8; ++n) acc[m][n] = fzero;

  // prologue: A regs + W glds for tile kt0
  #pragma unroll
  for (int i = 0; i < 8; ++i)
    areg[i] = *(const f32x4*)(aptr + (size_t)i * (16ull * FT_IN));
  #pragma unroll
  for (int i = 0; i < 8; ++i) {
    const unsigned short* g = wptr + (size_t)i * (32ull * FT_IN) + wkcs * 8;
    __builtin_amdgcn_global_load_lds((gas1_t)g,
        (las3_t)&sW[0][(i * 256 + tid) * 16], 16, 0, 0);
  }

  int buf = 0;
  for (int kt = kt0; kt < kt1; ++kt) {
    // phase A: cvt + store A tile (swizzle: byte ^= (row&7)<<4)
    #pragma unroll
    for (int i = 0; i < 8; ++i) {
      const int row = i * 16 + arow;
      f32x4 v = areg[i];
      uint32_t b0, b1;
      CVTPK(b0, v.x, v.y);
      CVTPK(b1, v.z, v.w);
      u32x2 b; b.x = b0; b.y = b1;
      *(u32x2*)(sA + row * 128 + ((akc * 8) ^ ((row & 7) << 4))) = b;
    }
    // barrier 1: full drain — only W(t) (issued one iteration ago) is
    // outstanding, so the vmcnt(0) is nearly free. sA(t)+sW[buf] visible.
    __syncthreads();

    // phase B: issue next tile's loads (stay in flight across barrier 2)
    if (kt + 1 < kt1) {
      const int d = kt + 1 - kt0;
      const float* ap = aptr + d * 64;
      #pragma unroll
      for (int i = 0; i < 8; ++i)
        areg[i] = *(const f32x4*)(ap + (size_t)i * (16ull * FT_IN));
      const unsigned short* wp = wptr + d * 64;
      #pragma unroll
      for (int i = 0; i < 8; ++i) {
        const unsigned short* g = wp + (size_t)i * (32ull * FT_IN) + wkcs * 8;
        __builtin_amdgcn_global_load_lds((gas1_t)g,
            (las3_t)&sW[buf ^ 1][(i * 256 + tid) * 16], 16, 0, 0);
      }
    }

    // phase C: MFMA
    const char* sWb = sW[buf];
    const int swz = (r16 & 7) << 4;
    #pragma unroll
    for (int k2 = 0; k2 < 2; ++k2) {
      const int ko = (k2 * 64 + hi * 16) ^ swz;
      short8 av[4], bv[8];
      #pragma unroll
      for (int m = 0; m < 4; ++m)
        av[m] = *(const short8*)(sA + (wr + m * 16 + r16) * 128 + ko);
      #pragma unroll
      for (int n = 0; n < 8; ++n)
        bv[n] = *(const short8*)(sWb + (wc + n * 16 + r16) * 128 + ko);
      #pragma unroll
      for (int m = 0; m < 4; ++m)
        #pragma unroll
        for (int n = 0; n < 8; ++n)
          MFMA16(acc[m][n], av[m], bv[n]);
    }

    // barrier 2: RAW s_barrier — no vmcnt drain; A(t+1)/W(t+1) stay in
    // flight through the next cvt phase (double-buffered sW -> no race).
    __builtin_amdgcn_sched_barrier(0);
    __builtin_amdgcn_s_barrier();
    __builtin_amdgcn_sched_barrier(0);
    buf ^= 1;
  }

  // epilogue: fp16 partials [ks*2+set][col][row] (RNE scalar casts; RTZ
  // pack would bias the K-sum). D frag: col = lane&15, row = (lane>>4)*4+reg.
  _Float16* pb = part + (size_t)(ks * 2 + st) * (KHALF * (size_t)BATCH);
  const int growb = rb * 128 + wr + hi * 4;
  const int gcolb = wc + r16;
  #pragma unroll
  for (int n = 0; n < 8; ++n)
    #pragma unroll
    for (int m = 0; m < 4; ++m) {
      f32x4 a = acc[m][n];
      half4v h;
      h.x = (_Float16)a.x; h.y = (_Float16)a.y;
      h.z = (_Float16)a.z; h.w = (_Float16)a.w;
      *(half4v*)(pb + (size_t)(gcolb + n * 16) * BATCH + (growb + m * 16)) = h;
    }
}

// ---------------- kernel 3: tail MLP ----------------
// 256 blocks x 32 rows. Thread (r = tid&31, cg = tid>>5): row r, 64 cols
// [cg*64, cg*64+64). a1-partials reduced across the 8 col-groups via LDS.
__global__ __launch_bounds__(256) void tail_kernel(
    const _Float16* __restrict__ part,
    const float* __restrict__ ftb, const float* __restrict__ h1w,
    const float* __restrict__ h1b, const float* __restrict__ h2w,
    const float* __restrict__ h2b, const float* __restrict__ outw,
    const float* __restrict__ outb, float* __restrict__ out, int KS) {
  __shared__ float sh1t[512 * 36];   // h1_w transposed [c][j], stride 36 (pad)
  __shared__ float sh2[32 * 32];
  __shared__ float sow[32];
  __shared__ float sh1b[32];
  __shared__ float sh2b[32];
  __shared__ float sftb[256];
  __shared__ float sob[1];

  const int tid = (int)threadIdx.x;
  // coalesced global read (c fast), strided LDS write
  for (int i = tid; i < 512 * 32; i += 256) {
    const int j = i >> 9, c = i & 511;
    sh1t[c * 36 + j] = h1w[i];       // h1w[j][c]
  }
  for (int i = tid; i < 1024; i += 256) sh2[i] = h2w[i];
  if (tid < 32) { sow[tid] = outw[tid]; sh1b[tid] = h1b[tid]; sh2b[tid] = h2b[tid]; }
  sftb[tid] = ftb[tid];
  if (tid == 0) sob[0] = outb[0];
  __syncthreads();

  const int r  = tid & 31;
  const int cg = tid >> 5;
  const int t  = (int)blockIdx.x * 32 + r;   // global batch row

  float a1p[32];
  #pragma unroll
  for (int j = 0; j < 32; ++j) a1p[j] = 0.f;

  for (int ci = 0; ci < 64; ++ci) {
    const int c   = cg * 64 + ci;
    const int set = c >> 8;
    const int cs  = c & 255;
    float v = sftb[cs];
    const _Float16* p = part + ((size_t)set * KHALF + cs) * BATCH + t;
    for (int kq = 0; kq < KS; ++kq)
      v += (float)p[(size_t)kq * (2ull * KHALF * BATCH)];
    v = fminf(fmaxf(v, 0.f), 1.f);
    const f32x4* wr4 = (const f32x4*)(sh1t + c * 36);
    #pragma unroll
    for (int q = 0; q < 8; ++q) {
      f32x4 wv = wr4[q];
      a1p[q * 4 + 0] += v * wv.x; a1p[q * 4 + 1] += v * wv.y;
      a1p[q * 4 + 2] += v * wv.z; a1p[q * 4 + 3] += v * wv.w;
    }
  }

  // reduce the 8 col-group partials per row via LDS (reuse sh1t region)
  float* red = sh1t;                  // [8][32][33]
  __syncthreads();
  #pragma unroll
  for (int j = 0; j < 32; ++j)
    red[(cg * 32 + r) * 33 + j] = a1p[j];
  __syncthreads();

  if (tid < 32) {
    float a1[32];
    #pragma unroll
    for (int j = 0; j < 32; ++j) a1[j] = sh1b[j];
    for (int g = 0; g < 8; ++g)
      #pragma unroll
      for (int j = 0; j < 32; ++j)
        a1[j] += red[(g * 32 + tid) * 33 + j];
    #pragma unroll
    for (int j = 0; j < 32; ++j) a1[j] = fminf(fmaxf(a1[j], 0.f), 1.f);

    float a2[32];
    #pragma unroll
    for (int j = 0; j < 32; ++j) {
      float x = sh2b[j];
      const f32x4* w2 = (const f32x4*)(sh2 + j * 32);
      #pragma unroll
      for (int q = 0; q < 8; ++q) {
        f32x4 wv = w2[q];
        x += a1[q * 4 + 0] * wv.x + a1[q * 4 + 1] * wv.y +
             a1[q * 4 + 2] * wv.z + a1[q * 4 + 3] * wv.w;
      }
      a2[j] = fminf(fmaxf(x, 0.f), 1.f);
    }
    float o = sob[0];
    #pragma unroll
    for (int j = 0; j < 32; ++j) o += a2[j] * sow[j];
    out[(int)blockIdx.x * 32 + tid] = o;
  }
}

// ---------------- launch ----------------
extern "C" void kernel_launch(void* const* d_in, const int* in_sizes, int n_in,
                              void* d_out, int out_size, void* d_ws, size_t ws_size,
                              hipStream_t stream) {
  const float* f1   = (const float*)d_in[0];
  const float* f2   = (const float*)d_in[1];
  const float* ftw  = (const float*)d_in[2];
  const float* ftb  = (const float*)d_in[3];
  const float* h1w  = (const float*)d_in[4];
  const float* h1b  = (const float*)d_in[5];
  const float* h2w  = (const float*)d_in[6];
  const float* h2b  = (const float*)d_in[7];
  const float* outw = (const float*)d_in[8];
  const float* outb = (const float*)d_in[9];
  float* out = (float*)d_out;

  unsigned short* wb = (unsigned short*)d_ws;
  const size_t woff = (size_t)KHALF * FT_IN * 2;            // 21,004,288 B
  _Float16* part = (_Float16*)((char*)d_ws + woff);
  const size_t per = 2ull * KHALF * BATCH * 2;              // 8,388,608 B / kchunk

  // KS=4 -> 64rb x 2set x 4 = 512 WGs = exactly 2 WGs/CU (80 KB LDS), 1 round
  int KS = 1;
  if (ws_size >= woff + 4 * per)      KS = 4;
  else if (ws_size >= woff + 2 * per) KS = 2;

  wprep_kernel<<<2048, 256, 0, stream>>>(ftw, wb, (KHALF * FT_IN) / 4);
  ftgemm_kernel<<<dim3(64 * 2 * KS), 256, 0, stream>>>(f1, f2, wb, part, KS);
  tail_kernel<<<BATCH / 32, 256, 0, stream>>>(part, ftb, h1w, h1b, h2w, h2b,
                                              outw, outb, out, KS);
}